// Round 5
// baseline (26255.865 us; speedup 1.0000x reference)
//
#include <hip/hip_runtime.h>
#include <hip/hip_bf16.h>

// ESN forward: states[s] = tanh(x[s] @ W_in^T + b + h_{s-1} @ W_hh^T)
// SEQ=1024, BATCH=64, IN=512, RES=2048, fp32 in/out.
// R5: decomposition 8 batch-groups x 8 batches, 32 WGs x 64 cols per group
// (halves h-broadcast fabric traffic); W_hh in VGPRs (128/thread); WG-
// cooperative full-line sentinel poll (wave w owns batch-row w) staged via
// LDS; ring 8 self-clocked (skew<=1 by all-to-all dependence), owner
// re-poisons slot s+4 each step; NO flags, NO barriers beyond 2 syncthreads.
// All cross-WG traffic relaxed agent-scope atomics (IF$-coherent).

#define SEQ  1024
#define NB   64
#define INF  512
#define RES  2048
#define RING 8

typedef float    f32x4 __attribute__((ext_vector_type(4)));
typedef _Float16 f16x8 __attribute__((ext_vector_type(8)));

__device__ __forceinline__ float fast_tanh(float x) {
  const float e = __expf(2.0f * x);
  return 1.0f - 2.0f * __builtin_amdgcn_rcpf(1.0f + e);
}

// ---------------------------------------------------------------------------
// Kernel B: U = X @ Win^T + bias   (M=65536, N=2048, K=512), U -> d_out states
// ---------------------------------------------------------------------------
__global__ __launch_bounds__(256) void xin_gemm(
    const float* __restrict__ X, const float* __restrict__ Win,
    const float* __restrict__ bias, float* __restrict__ U)
{
  __shared__ _Float16 lA[2][128][40];
  __shared__ _Float16 lB[2][128][40];

  const int tid  = threadIdx.x;
  const int lane = tid & 63;
  const int wv   = tid >> 6;
  const int wr   = wv >> 1;
  const int wc   = wv & 1;
  const int m0   = (blockIdx.x >> 4) * 128;
  const int n0   = (blockIdx.x & 15) * 128;

  const int srow = tid >> 1;
  const int sk   = (tid & 1) * 16;

  const int fr = lane & 15;
  const int fk = (lane >> 4) * 8;

  f32x4 acc[4][4] = {};
  float ra[16], rb[16];

  const float* xa_base = X   + (size_t)(m0 + srow) * INF + sk;
  const float* xb_base = Win + (size_t)(n0 + srow) * INF + sk;

#define LOADK(kt) do {                                                     \
    const float* pa = xa_base + (kt) * 32;                                 \
    const float* pb = xb_base + (kt) * 32;                                 \
    *(f32x4*)&ra[0]  = *(const f32x4*)(pa + 0);                            \
    *(f32x4*)&ra[4]  = *(const f32x4*)(pa + 4);                            \
    *(f32x4*)&ra[8]  = *(const f32x4*)(pa + 8);                            \
    *(f32x4*)&ra[12] = *(const f32x4*)(pa + 12);                           \
    *(f32x4*)&rb[0]  = *(const f32x4*)(pb + 0);                            \
    *(f32x4*)&rb[4]  = *(const f32x4*)(pb + 4);                            \
    *(f32x4*)&rb[8]  = *(const f32x4*)(pb + 8);                            \
    *(f32x4*)&rb[12] = *(const f32x4*)(pb + 12);                           \
  } while (0)

#define STOREK(buf) do {                                                   \
    f16x8 h0, h1;                                                          \
    _Pragma("unroll") for (int j = 0; j < 8; ++j) h0[j] = (_Float16)ra[j]; \
    _Pragma("unroll") for (int j = 0; j < 8; ++j) h1[j] = (_Float16)ra[8+j];\
    *(f16x8*)&lA[buf][srow][sk]     = h0;                                  \
    *(f16x8*)&lA[buf][srow][sk + 8] = h1;                                  \
    _Pragma("unroll") for (int j = 0; j < 8; ++j) h0[j] = (_Float16)rb[j]; \
    _Pragma("unroll") for (int j = 0; j < 8; ++j) h1[j] = (_Float16)rb[8+j];\
    *(f16x8*)&lB[buf][srow][sk]     = h0;                                  \
    *(f16x8*)&lB[buf][srow][sk + 8] = h1;                                  \
  } while (0)

#define COMPUTE(buf) do {                                                  \
    f16x8 af[4], bf[4];                                                    \
    _Pragma("unroll") for (int mt = 0; mt < 4; ++mt)                       \
      af[mt] = *(const f16x8*)&lA[buf][wr*64 + mt*16 + fr][fk];            \
    _Pragma("unroll") for (int nt = 0; nt < 4; ++nt)                       \
      bf[nt] = *(const f16x8*)&lB[buf][wc*64 + nt*16 + fr][fk];            \
    _Pragma("unroll") for (int mt = 0; mt < 4; ++mt)                       \
      _Pragma("unroll") for (int nt = 0; nt < 4; ++nt)                     \
        acc[mt][nt] = __builtin_amdgcn_mfma_f32_16x16x32_f16(              \
            af[mt], bf[nt], acc[mt][nt], 0, 0, 0);                         \
  } while (0)

  LOADK(0);
  STOREK(0);
  __syncthreads();

#pragma unroll 1
  for (int kt = 0; kt < 16; ++kt) {
    const int buf = kt & 1;
    if (kt < 15) LOADK(kt + 1);
    COMPUTE(buf);
    if (kt < 15) STOREK(buf ^ 1);
    __syncthreads();
  }

#pragma unroll
  for (int mt = 0; mt < 4; ++mt) {
    const int row = m0 + wr*64 + mt*16 + (lane >> 4) * 4;
#pragma unroll
    for (int nt = 0; nt < 4; ++nt) {
      const int col = n0 + wc*64 + nt*16 + fr;
      const float bv = bias[col];
#pragma unroll
      for (int i = 0; i < 4; ++i)
        U[(size_t)(row + i) * RES + col] = acc[mt][nt][i] + bv;
    }
  }
#undef LOADK
#undef STOREK
#undef COMPUTE
}

// ---------------------------------------------------------------------------
// Kernel C: persistent recurrence. 256 WGs x 512 thr, 1 WG/CU.
// WG = (batch group g: 8 batches) x (col range c0..c0+64).
// 8 waves = 4 K-quarters (kQ) x 2 col-halves (ctH); each wave: 2 col-tiles,
// 16 K-steps, W in VGPR (wf[2][16] = 128 VGPR).
// Poll: wave w cooperatively loads batch-row w of ring slot s-1 (64 B/lane,
// full-line), NaN-sentinel retry per-wave, stage to LDS; MFMA A-frags from
// LDS. Reduce: 4-way via parity-double-buffered LDS; epilogue on waves 0/1;
// poison by waves 4..7 (slot s+4). No flags, no epoch barrier.
// ---------------------------------------------------------------------------
__global__ __launch_bounds__(512, 2) void esn_recur(
    const float* __restrict__ Whh, float* __restrict__ states,
    float* __restrict__ hn, _Float16* __restrict__ ring)
{
  __shared__ _Float16 hl[8 * 2056];            // 32.9 KB staged h (pad 8 halfs)
  __shared__ f32x4    red[2][3][2][2][64];     // 24.6 KB parity-dbuf reduce

  const int tid  = threadIdx.x;
  const int lane = tid & 63;
  const int wv   = tid >> 6;
  const int kQ   = wv >> 1;        // K-quarter 0..3 (512 cols of K each)
  const int ctH  = wv & 1;         // col-half 0..1 (32 cols each)

  const int bid = blockIdx.x;
  const int g   = bid & 7;         // batch group (8 batches); %8 ~ XCD
  const int b0  = g * 8;
  const int c0  = (bid >> 3) * 64;

  const int fr = lane & 15;
  const int fk = (lane >> 4) * 8;

  // ---- one-time: W_hh fragments -> VGPRs (32 x f16x8 = 128 VGPR) ----
  f16x8 wf[2][16];
#pragma unroll 1
  for (int ct2 = 0; ct2 < 2; ++ct2)
#pragma unroll
    for (int ks = 0; ks < 16; ++ks) {
      const float* src = Whh + (size_t)(c0 + (ctH*2 + ct2)*16 + fr) * RES
                       + kQ*512 + ks*32 + fk;
      const f32x4 w0 = *(const f32x4*)src;
      const f32x4 w1 = *(const f32x4*)(src + 4);
      f16x8 f;
#pragma unroll
      for (int j = 0; j < 4; ++j) { f[j] = (_Float16)w0[j]; f[4+j] = (_Float16)w1[j]; }
      wf[ct2][ks] = f;
    }

  const bool epi = (kQ == 0) && ((lane >> 4) < 2);   // epilogue-active lanes

  for (int s = 0; s < SEQ; ++s) {
    // u prefetch (epilogue lanes only; hides HBM latency under poll+MFMA)
    float u[2][4];
    if (epi) {
      const float* up = states + (size_t)s * NB * RES;
#pragma unroll
      for (int ct2 = 0; ct2 < 2; ++ct2) {
        const int col = c0 + (ctH*2 + ct2)*16 + fr;
#pragma unroll
        for (int i = 0; i < 4; ++i)
          u[ct2][i] = up[(size_t)(b0 + (lane >> 4)*4 + i) * RES + col];
      }
    }

    // ---- cooperative sentinel poll: wave wv owns batch-row wv ----
    unsigned long long d[8];
    if (s > 0) {
      const _Float16* hp = ring + (size_t)((s - 1) & (RING - 1)) * (NB * RES)
                         + (size_t)(b0 + wv) * RES + lane * 32;
      for (;;) {
#pragma unroll
        for (int k = 0; k < 8; ++k)
          d[k] = __hip_atomic_load((const unsigned long long*)hp + k,
                                   __ATOMIC_RELAXED, __HIP_MEMORY_SCOPE_AGENT);
        union { unsigned long long q[2]; f16x8 v; } p0, p1, p2, p3;
        p0.q[0]=d[0]; p0.q[1]=d[1]; p1.q[0]=d[2]; p1.q[1]=d[3];
        p2.q[0]=d[4]; p2.q[1]=d[5]; p3.q[0]=d[6]; p3.q[1]=d[7];
        const f16x8 ss = (p0.v + p1.v) + (p2.v + p3.v);   // NaN propagates
        union { f16x8 v; unsigned w[4]; } su; su.v = ss;
        unsigned bad = 0;
#pragma unroll
        for (int j = 0; j < 4; ++j) {
          bad |= ((su.w[j] & 0x7C00u) == 0x7C00u);
          bad |= (((su.w[j] >> 16) & 0x7C00u) == 0x7C00u);
        }
        if (!__any(bad)) break;
      }
      _Float16* dst = hl + wv * 2056 + lane * 32;
#pragma unroll
      for (int k = 0; k < 4; ++k) {
        union { unsigned long long q[2]; f16x8 v; } p;
        p.q[0] = d[2*k]; p.q[1] = d[2*k + 1];
        *(f16x8*)(dst + k * 8) = p.v;
      }
    }
    __syncthreads();   // hl ready

    // ---- MFMA: 2 col-tiles x 16 K-steps ----
    f32x4 acc0 = {0.f, 0.f, 0.f, 0.f}, acc1 = {0.f, 0.f, 0.f, 0.f};
    if (s > 0) {
      const int  arow = lane & 15;
      const bool av   = arow < 8;
      const _Float16* ab = hl + arow * 2056 + kQ * 512 + fk;
#pragma unroll
      for (int ks = 0; ks < 16; ++ks) {
        f16x8 a = {};
        if (av) a = *(const f16x8*)(ab + ks * 32);
        acc0 = __builtin_amdgcn_mfma_f32_16x16x32_f16(a, wf[0][ks], acc0, 0, 0, 0);
        acc1 = __builtin_amdgcn_mfma_f32_16x16x32_f16(a, wf[1][ks], acc1, 0, 0, 0);
      }
    }

    if (kQ > 0) {
      red[s & 1][kQ - 1][ctH][0][lane] = acc0;
      red[s & 1][kQ - 1][ctH][1][lane] = acc1;
    }
    __syncthreads();   // red ready

    if (kQ == 0) {
#pragma unroll
      for (int j = 0; j < 3; ++j) {
        acc0 += red[s & 1][j][ctH][0][lane];
        acc1 += red[s & 1][j][ctH][1][lane];
      }
      if (epi) {
        float* up = states + (size_t)s * NB * RES;
        unsigned short* hc = (unsigned short*)(ring
                           + (size_t)(s & (RING - 1)) * (NB * RES));
#pragma unroll
        for (int ct2 = 0; ct2 < 2; ++ct2) {
          const int col = c0 + (ctH*2 + ct2)*16 + fr;
          const f32x4 a = ct2 ? acc1 : acc0;
#pragma unroll
          for (int i = 0; i < 4; ++i) {
            const int r = (lane >> 4) * 4 + i;
            const size_t off = (size_t)(b0 + r) * RES + col;
            const float v = fast_tanh(u[ct2][i] + a[i]);
            up[off] = v;                                   // states[s] (private)
            const _Float16 vh = (_Float16)v;
            __hip_atomic_store(hc + off, __builtin_bit_cast(unsigned short, vh),
                               __ATOMIC_RELAXED, __HIP_MEMORY_SCOPE_AGENT);
            if (s == SEQ - 1) hn[off] = v;
          }
        }
      }
    } else if (kQ >= 2) {
      // poison slot s+4 (own cells: rows 0..7 x cols c0..c0+64).
      // Safe: skew<=1 (all-to-all dep) => no reader is within 3 steps of this
      // slot; completion ordered ahead of our step-s+4 data by own poll vmcnt.
      const int j   = wv - 4;                 // 0..3
      const int row = 2*j + (lane >> 5);      // 0..7
      unsigned* pz = (unsigned*)(ring + (size_t)((s + 4) & (RING - 1)) * (NB * RES)
                   + (size_t)(b0 + row) * RES + c0);
      __hip_atomic_store(pz + (lane & 31), 0x7F7F7F7Fu,
                         __ATOMIC_RELAXED, __HIP_MEMORY_SCOPE_AGENT);
    }
    // no step-end barrier: next-step hl writes are gated by red-sync; red is
    // parity-double-buffered; ring slots are sentinel-gated.
  }
}

// ---------------------------------------------------------------------------
extern "C" void kernel_launch(void* const* d_in, const int* in_sizes, int n_in,
                              void* d_out, int out_size, void* d_ws, size_t ws_size,
                              hipStream_t stream) {
  const float* x    = (const float*)d_in[0];
  const float* W_in = (const float*)d_in[1];
  const float* W_hh = (const float*)d_in[2];
  const float* bias = (const float*)d_in[3];

  float* states = (float*)d_out;                        // [1024][64][2048]
  float* hn     = states + (size_t)SEQ * NB * RES;      // [64][2048]

  _Float16* ring = (_Float16*)d_ws;                     // RING x [64][2048] fp16

  // sentinel-init ring (0x7F7F = fp16 NaN)
  hipMemsetAsync(ring, 0x7F, (size_t)RING * NB * RES * sizeof(_Float16), stream);

  xin_gemm<<<dim3(512 * 16), dim3(256), 0, stream>>>(x, W_in, bias, states);
  esn_recur<<<dim3(256), dim3(512), 0, stream>>>(W_hh, states, hn, ring);
}

// Round 6
// 13829.269 us; speedup vs baseline: 1.8986x; 1.8986x over previous
//
#include <hip/hip_runtime.h>
#include <hip/hip_bf16.h>

// ESN forward: states[s] = tanh(x[s] @ W_in^T + b + h_{s-1} @ W_hh^T)
// SEQ=1024, BATCH=64, IN=512, RES=2048, fp32 in/out.
// R6: 8 batch-groups x 8 batches, 32 WGs x 64 cols per group (halved
// broadcast); W_hh in VGPRs (wf[4][8]=128 VGPR, launch_bounds(512,1) --
// R5's (512,2) capped VGPRs at 128 and forced W rematerialization from
// global = 34.5 GB/dispatch). h is read DIRECTLY in MFMA fragment layout
// from the NaN-sentinel ring (full 64B-line coverage, no LDS staging ->
// no bank conflicts). Ring-8 self-clocked (all-to-all => skew<=1), slot
// s+4 re-poisoned each step, parity-dbuf LDS reduce, 1 syncthreads/step.

#define SEQ  1024
#define NB   64
#define INF  512
#define RES  2048
#define RING 8

typedef float    f32x4 __attribute__((ext_vector_type(4)));
typedef _Float16 f16x8 __attribute__((ext_vector_type(8)));

__device__ __forceinline__ float fast_tanh(float x) {
  const float e = __expf(2.0f * x);
  return 1.0f - 2.0f * __builtin_amdgcn_rcpf(1.0f + e);
}

// ---------------------------------------------------------------------------
// Kernel B: U = X @ Win^T + bias   (M=65536, N=2048, K=512), U -> d_out states
// ---------------------------------------------------------------------------
__global__ __launch_bounds__(256) void xin_gemm(
    const float* __restrict__ X, const float* __restrict__ Win,
    const float* __restrict__ bias, float* __restrict__ U)
{
  __shared__ _Float16 lA[2][128][40];
  __shared__ _Float16 lB[2][128][40];

  const int tid  = threadIdx.x;
  const int lane = tid & 63;
  const int wv   = tid >> 6;
  const int wr   = wv >> 1;
  const int wc   = wv & 1;
  const int m0   = (blockIdx.x >> 4) * 128;
  const int n0   = (blockIdx.x & 15) * 128;

  const int srow = tid >> 1;
  const int sk   = (tid & 1) * 16;

  const int fr = lane & 15;
  const int fk = (lane >> 4) * 8;

  f32x4 acc[4][4] = {};
  float ra[16], rb[16];

  const float* xa_base = X   + (size_t)(m0 + srow) * INF + sk;
  const float* xb_base = Win + (size_t)(n0 + srow) * INF + sk;

#define LOADK(kt) do {                                                     \
    const float* pa = xa_base + (kt) * 32;                                 \
    const float* pb = xb_base + (kt) * 32;                                 \
    *(f32x4*)&ra[0]  = *(const f32x4*)(pa + 0);                            \
    *(f32x4*)&ra[4]  = *(const f32x4*)(pa + 4);                            \
    *(f32x4*)&ra[8]  = *(const f32x4*)(pa + 8);                            \
    *(f32x4*)&ra[12] = *(const f32x4*)(pa + 12);                           \
    *(f32x4*)&rb[0]  = *(const f32x4*)(pb + 0);                            \
    *(f32x4*)&rb[4]  = *(const f32x4*)(pb + 4);                            \
    *(f32x4*)&rb[8]  = *(const f32x4*)(pb + 8);                            \
    *(f32x4*)&rb[12] = *(const f32x4*)(pb + 12);                           \
  } while (0)

#define STOREK(buf) do {                                                   \
    f16x8 h0, h1;                                                          \
    _Pragma("unroll") for (int j = 0; j < 8; ++j) h0[j] = (_Float16)ra[j]; \
    _Pragma("unroll") for (int j = 0; j < 8; ++j) h1[j] = (_Float16)ra[8+j];\
    *(f16x8*)&lA[buf][srow][sk]     = h0;                                  \
    *(f16x8*)&lA[buf][srow][sk + 8] = h1;                                  \
    _Pragma("unroll") for (int j = 0; j < 8; ++j) h0[j] = (_Float16)rb[j]; \
    _Pragma("unroll") for (int j = 0; j < 8; ++j) h1[j] = (_Float16)rb[8+j];\
    *(f16x8*)&lB[buf][srow][sk]     = h0;                                  \
    *(f16x8*)&lB[buf][srow][sk + 8] = h1;                                  \
  } while (0)

#define COMPUTE(buf) do {                                                  \
    f16x8 af[4], bf[4];                                                    \
    _Pragma("unroll") for (int mt = 0; mt < 4; ++mt)                       \
      af[mt] = *(const f16x8*)&lA[buf][wr*64 + mt*16 + fr][fk];            \
    _Pragma("unroll") for (int nt = 0; nt < 4; ++nt)                       \
      bf[nt] = *(const f16x8*)&lB[buf][wc*64 + nt*16 + fr][fk];            \
    _Pragma("unroll") for (int mt = 0; mt < 4; ++mt)                       \
      _Pragma("unroll") for (int nt = 0; nt < 4; ++nt)                     \
        acc[mt][nt] = __builtin_amdgcn_mfma_f32_16x16x32_f16(              \
            af[mt], bf[nt], acc[mt][nt], 0, 0, 0);                         \
  } while (0)

  LOADK(0);
  STOREK(0);
  __syncthreads();

#pragma unroll 1
  for (int kt = 0; kt < 16; ++kt) {
    const int buf = kt & 1;
    if (kt < 15) LOADK(kt + 1);
    COMPUTE(buf);
    if (kt < 15) STOREK(buf ^ 1);
    __syncthreads();
  }

#pragma unroll
  for (int mt = 0; mt < 4; ++mt) {
    const int row = m0 + wr*64 + mt*16 + (lane >> 4) * 4;
#pragma unroll
    for (int nt = 0; nt < 4; ++nt) {
      const int col = n0 + wc*64 + nt*16 + fr;
      const float bv = bias[col];
#pragma unroll
      for (int i = 0; i < 4; ++i)
        U[(size_t)(row + i) * RES + col] = acc[mt][nt][i] + bv;
    }
  }
#undef LOADK
#undef STOREK
#undef COMPUTE
}

// ---------------------------------------------------------------------------
// Kernel C: persistent recurrence. 256 WGs x 512 thr, 1 WG/CU.
// WG = (batch group g: 8 batches) x (cols c0..c0+64). Wave q = K-eighth.
// Each wave: A-frags (rows 0..7 x K[256q,256q+256)) polled directly from
// ring (sentinel = fp16 NaN); B = wf[4][8] in VGPR; 32 MFMA.
// Reduce: parity-dbuf LDS, waves 0/1 finalize tiles 0-1 / 2-3; epilogue on
// lanes 0-31 of waves 0/1. Waves 2-5 poison slot s+4. 1 syncthreads/step.
// ---------------------------------------------------------------------------
__global__ __launch_bounds__(512, 1) void esn_recur(
    const float* __restrict__ Whh, float* __restrict__ states,
    float* __restrict__ hn, _Float16* __restrict__ ring)
{
  __shared__ f32x4 red0[2][7][2][64];   // 28 KB: tiles 0-1 partials
  __shared__ f32x4 red1[2][7][2][64];   // 28 KB: tiles 2-3 partials

  const int tid  = threadIdx.x;
  const int lane = tid & 63;
  const int wv   = tid >> 6;        // wave = K-eighth q
  const int q    = wv;

  const int bid = blockIdx.x;
  const int g   = bid & 7;          // batch group; %8 ~ XCD
  const int b0  = g * 8;
  const int c0  = (bid >> 3) * 64;

  const int fr = lane & 15;
  const int fk = (lane >> 4) * 8;
  const bool av = fr < 8;           // valid A row (8 batches per group)

  // ---- one-time: W_hh fragments -> VGPRs (32 x f16x8 = 128 VGPR) ----
  f16x8 wf[4][8];
#pragma unroll
  for (int t = 0; t < 4; ++t)
#pragma unroll
    for (int ks = 0; ks < 8; ++ks) {
      const float* src = Whh + (size_t)(c0 + t*16 + fr) * RES
                       + q*256 + ks*32 + fk;
      const f32x4 w0 = *(const f32x4*)src;
      const f32x4 w1 = *(const f32x4*)(src + 4);
      f16x8 f;
#pragma unroll
      for (int j = 0; j < 4; ++j) { f[j] = (_Float16)w0[j]; f[4+j] = (_Float16)w1[j]; }
      wf[t][ks] = f;
    }

  const bool epi = (wv < 2) && ((lane >> 4) < 2);   // epilogue lanes (rows 0-7)

  for (int s = 0; s < SEQ; ++s) {
    // u prefetch (epilogue lanes; overlaps poll+MFMA)
    float u[2][4];
    if (epi) {
      const float* up = states + (size_t)s * NB * RES;
#pragma unroll
      for (int tt = 0; tt < 2; ++tt) {
        const int col = c0 + (wv*2 + tt)*16 + fr;
#pragma unroll
        for (int i = 0; i < 4; ++i)
          u[tt][i] = up[(size_t)(b0 + (lane >> 4)*4 + i) * RES + col];
      }
    }

    f32x4 acc[4] = {};

    if (s > 0) {
      // ---- sentinel poll in fragment layout (full-line coverage) ----
      const _Float16* hp = ring + (size_t)((s - 1) & (RING - 1)) * (NB * RES)
                         + (size_t)(b0 + fr) * RES + q*256 + fk;
      f16x8 hv[8];
#pragma unroll
      for (int k = 0; k < 8; ++k) hv[k] = f16x8{};
      for (;;) {
        if (av) {
#pragma unroll
          for (int ks = 0; ks < 8; ++ks) {
            union { unsigned long long w[2]; f16x8 v; } au;
            au.w[0] = __hip_atomic_load((const unsigned long long*)(hp + ks*32),
                                        __ATOMIC_RELAXED, __HIP_MEMORY_SCOPE_AGENT);
            au.w[1] = __hip_atomic_load((const unsigned long long*)(hp + ks*32 + 4),
                                        __ATOMIC_RELAXED, __HIP_MEMORY_SCOPE_AGENT);
            hv[ks] = au.v;
          }
        }
        unsigned bad = 0;
        if (av) {
          const f16x8 ss = ((hv[0] + hv[1]) + (hv[2] + hv[3]))
                         + ((hv[4] + hv[5]) + (hv[6] + hv[7]));   // NaN propagates
          union { f16x8 v; unsigned w[4]; } su; su.v = ss;
#pragma unroll
          for (int j = 0; j < 4; ++j) {
            bad |= ((su.w[j] & 0x7C00u) == 0x7C00u);
            bad |= (((su.w[j] >> 16) & 0x7C00u) == 0x7C00u);
          }
        }
        if (!__any(bad)) break;
      }
      // ---- 4 col-tiles x 8 K-steps ----
#pragma unroll
      for (int ks = 0; ks < 8; ++ks) {
#pragma unroll
        for (int t = 0; t < 4; ++t)
          acc[t] = __builtin_amdgcn_mfma_f32_16x16x32_f16(hv[ks], wf[t][ks], acc[t], 0, 0, 0);
      }
    }

    const int p = s & 1;
    if (wv != 0) {
      red0[p][wv - 1][0][lane] = acc[0];
      red0[p][wv - 1][1][lane] = acc[1];
    }
    if (wv != 1) {
      const int j = (wv == 0) ? 0 : wv - 1;
      red1[p][j][0][lane] = acc[2];
      red1[p][j][1][lane] = acc[3];
    }
    __syncthreads();

    if (wv < 2) {
      f32x4 r0 = acc[wv*2 + 0], r1 = acc[wv*2 + 1];
      const f32x4 (* __restrict__ rp)[2][64] = wv ? red1[p] : red0[p];
#pragma unroll
      for (int j = 0; j < 7; ++j) { r0 += rp[j][0][lane]; r1 += rp[j][1][lane]; }

      if (epi) {
        float* up = states + (size_t)s * NB * RES;
        unsigned short* hc = (unsigned short*)(ring
                           + (size_t)(s & (RING - 1)) * (NB * RES));
#pragma unroll
        for (int tt = 0; tt < 2; ++tt) {
          const int col = c0 + (wv*2 + tt)*16 + fr;
          const f32x4 a = tt ? r1 : r0;
#pragma unroll
          for (int i = 0; i < 4; ++i) {
            const int r = (lane >> 4) * 4 + i;
            const size_t off = (size_t)(b0 + r) * RES + col;
            const float v = fast_tanh(u[tt][i] + a[i]);
            up[off] = v;                                   // states[s] (private)
            const _Float16 vh = (_Float16)v;
            __hip_atomic_store(hc + off, __builtin_bit_cast(unsigned short, vh),
                               __ATOMIC_RELAXED, __HIP_MEMORY_SCOPE_AGENT);
            if (s == SEQ - 1) hn[off] = v;
          }
        }
      }
    } else if (wv >= 2 && wv <= 5) {
      // poison slot s+4, own region (8 rows x 64 cols fp16 = 1KB).
      // Ordering: this wave's step-s+1 poll waits vmcnt(0) (drains this
      // store) before it can pass; epilogue's slot-(s+4) data store happens
      // after syncthreads(s+1) -> poison provably lands first.
      const int row = 2*(wv - 2) + (lane >> 5);
      unsigned* pz = (unsigned*)(ring + (size_t)((s + 4) & (RING - 1)) * (NB * RES)
                   + (size_t)(b0 + row) * RES + c0);
      __hip_atomic_store(pz + (lane & 31), 0x7F7F7F7Fu,
                         __ATOMIC_RELAXED, __HIP_MEMORY_SCOPE_AGENT);
    }
    // no step-end barrier: red is parity-double-buffered; ring is
    // sentinel-gated; skew<=1 by all-to-all dependence within the group.
  }
}

// ---------------------------------------------------------------------------
extern "C" void kernel_launch(void* const* d_in, const int* in_sizes, int n_in,
                              void* d_out, int out_size, void* d_ws, size_t ws_size,
                              hipStream_t stream) {
  const float* x    = (const float*)d_in[0];
  const float* W_in = (const float*)d_in[1];
  const float* W_hh = (const float*)d_in[2];
  const float* bias = (const float*)d_in[3];

  float* states = (float*)d_out;                        // [1024][64][2048]
  float* hn     = states + (size_t)SEQ * NB * RES;      // [64][2048]

  _Float16* ring = (_Float16*)d_ws;                     // RING x [64][2048] fp16

  // sentinel-init ring (0x7F7F = fp16 NaN)
  hipMemsetAsync(ring, 0x7F, (size_t)RING * NB * RES * sizeof(_Float16), stream);

  xin_gemm<<<dim3(512 * 16), dim3(256), 0, stream>>>(x, W_in, bias, states);
  esn_recur<<<dim3(256), dim3(512), 0, stream>>>(W_hh, states, hn, ring);
}

// Round 7
// 7529.294 us; speedup vs baseline: 3.4872x; 1.8367x over previous
//
#include <hip/hip_runtime.h>
#include <hip/hip_bf16.h>

// ESN forward: states[s] = tanh(x[s] @ W_in^T + b + h_{s-1} @ W_hh^T)
// SEQ=1024, BATCH=64, IN=512, RES=2048, fp32 in/out.
// R7 = R6 geometry (8 batch-groups x 8 batches, 32 WGs x 64 cols, W_hh in
// VGPRs, direct fragment-layout NaN-sentinel ring polls, ring-8, per-step
// poison of slot s+4) + congestion fixes:
//  - 8-step group flag-barrier restored (R4 cadence): bounds WG drift.
//  - s_sleep(1) backoff in data-polls: caps spin-load storm (R6: 4x VALU).
//  - all-wave epilogue: col-major reduce scratch, 1 output value/thread,
//    producer h-stores spread across all 8 waves.

#define SEQ  1024
#define NB   64
#define INF  512
#define RES  2048
#define RING 8

typedef float    f32x4 __attribute__((ext_vector_type(4)));
typedef _Float16 f16x8 __attribute__((ext_vector_type(8)));

__device__ __forceinline__ float fast_tanh(float x) {
  const float e = __expf(2.0f * x);
  return 1.0f - 2.0f * __builtin_amdgcn_rcpf(1.0f + e);
}

// ---------------------------------------------------------------------------
// Kernel B: U = X @ Win^T + bias   (M=65536, N=2048, K=512), U -> d_out states
// ---------------------------------------------------------------------------
__global__ __launch_bounds__(256) void xin_gemm(
    const float* __restrict__ X, const float* __restrict__ Win,
    const float* __restrict__ bias, float* __restrict__ U)
{
  __shared__ _Float16 lA[2][128][40];
  __shared__ _Float16 lB[2][128][40];

  const int tid  = threadIdx.x;
  const int lane = tid & 63;
  const int wv   = tid >> 6;
  const int wr   = wv >> 1;
  const int wc   = wv & 1;
  const int m0   = (blockIdx.x >> 4) * 128;
  const int n0   = (blockIdx.x & 15) * 128;

  const int srow = tid >> 1;
  const int sk   = (tid & 1) * 16;

  const int fr = lane & 15;
  const int fk = (lane >> 4) * 8;

  f32x4 acc[4][4] = {};
  float ra[16], rb[16];

  const float* xa_base = X   + (size_t)(m0 + srow) * INF + sk;
  const float* xb_base = Win + (size_t)(n0 + srow) * INF + sk;

#define LOADK(kt) do {                                                     \
    const float* pa = xa_base + (kt) * 32;                                 \
    const float* pb = xb_base + (kt) * 32;                                 \
    *(f32x4*)&ra[0]  = *(const f32x4*)(pa + 0);                            \
    *(f32x4*)&ra[4]  = *(const f32x4*)(pa + 4);                            \
    *(f32x4*)&ra[8]  = *(const f32x4*)(pa + 8);                            \
    *(f32x4*)&ra[12] = *(const f32x4*)(pa + 12);                           \
    *(f32x4*)&rb[0]  = *(const f32x4*)(pb + 0);                            \
    *(f32x4*)&rb[4]  = *(const f32x4*)(pb + 4);                            \
    *(f32x4*)&rb[8]  = *(const f32x4*)(pb + 8);                            \
    *(f32x4*)&rb[12] = *(const f32x4*)(pb + 12);                           \
  } while (0)

#define STOREK(buf) do {                                                   \
    f16x8 h0, h1;                                                          \
    _Pragma("unroll") for (int j = 0; j < 8; ++j) h0[j] = (_Float16)ra[j]; \
    _Pragma("unroll") for (int j = 0; j < 8; ++j) h1[j] = (_Float16)ra[8+j];\
    *(f16x8*)&lA[buf][srow][sk]     = h0;                                  \
    *(f16x8*)&lA[buf][srow][sk + 8] = h1;                                  \
    _Pragma("unroll") for (int j = 0; j < 8; ++j) h0[j] = (_Float16)rb[j]; \
    _Pragma("unroll") for (int j = 0; j < 8; ++j) h1[j] = (_Float16)rb[8+j];\
    *(f16x8*)&lB[buf][srow][sk]     = h0;                                  \
    *(f16x8*)&lB[buf][srow][sk + 8] = h1;                                  \
  } while (0)

#define COMPUTE(buf) do {                                                  \
    f16x8 af[4], bf[4];                                                    \
    _Pragma("unroll") for (int mt = 0; mt < 4; ++mt)                       \
      af[mt] = *(const f16x8*)&lA[buf][wr*64 + mt*16 + fr][fk];            \
    _Pragma("unroll") for (int nt = 0; nt < 4; ++nt)                       \
      bf[nt] = *(const f16x8*)&lB[buf][wc*64 + nt*16 + fr][fk];            \
    _Pragma("unroll") for (int mt = 0; mt < 4; ++mt)                       \
      _Pragma("unroll") for (int nt = 0; nt < 4; ++nt)                     \
        acc[mt][nt] = __builtin_amdgcn_mfma_f32_16x16x32_f16(              \
            af[mt], bf[nt], acc[mt][nt], 0, 0, 0);                         \
  } while (0)

  LOADK(0);
  STOREK(0);
  __syncthreads();

#pragma unroll 1
  for (int kt = 0; kt < 16; ++kt) {
    const int buf = kt & 1;
    if (kt < 15) LOADK(kt + 1);
    COMPUTE(buf);
    if (kt < 15) STOREK(buf ^ 1);
    __syncthreads();
  }

#pragma unroll
  for (int mt = 0; mt < 4; ++mt) {
    const int row = m0 + wr*64 + mt*16 + (lane >> 4) * 4;
#pragma unroll
    for (int nt = 0; nt < 4; ++nt) {
      const int col = n0 + wc*64 + nt*16 + fr;
      const float bv = bias[col];
#pragma unroll
      for (int i = 0; i < 4; ++i)
        U[(size_t)(row + i) * RES + col] = acc[mt][nt][i] + bv;
    }
  }
#undef LOADK
#undef STOREK
#undef COMPUTE
}

// ---------------------------------------------------------------------------
// Kernel C: persistent recurrence. 256 WGs x 512 thr, 1 WG/CU.
// WG = (batch group g: 8 batches) x (cols c0..c0+64). Wave q = K-eighth.
// MFMA A-frags polled directly from NaN-sentinel ring (s_sleep backoff).
// Reduce: col-major red[parity][8][64][12] f32; finalize 1 value/thread
// (r=lane>>3, c=wv*8+(lane&7)); every wave stores its own 8-col h slice.
// Poison slot s+4 (1 elem/thread). Group flag-barrier every 8 steps.
// ---------------------------------------------------------------------------
__global__ __launch_bounds__(512, 1) void esn_recur(
    const float* __restrict__ Whh, float* __restrict__ states,
    float* __restrict__ hn, _Float16* __restrict__ ring,
    unsigned* __restrict__ flags)
{
  __shared__ float red[2][8][64][12];   // 49 KB, pad 12 -> <=2-way banks

  const int tid  = threadIdx.x;
  const int lane = tid & 63;
  const int wv   = tid >> 6;        // wave = K-eighth q
  const int q    = wv;

  const int bid = blockIdx.x;
  const int g   = bid & 7;          // batch group
  const int idx = bid >> 3;         // WG index within group 0..31
  const int b0  = g * 8;
  const int c0  = idx * 64;

  const int fr = lane & 15;
  const int fk = (lane >> 4) * 8;
  const bool av = fr < 8;           // valid A row (8 batches/group)

  // epilogue mapping: 1 value/thread
  const int er = lane >> 3;         // batch row 0..7
  const int ec = wv * 8 + (lane & 7);   // col 0..63

  // ---- one-time: W_hh fragments -> VGPRs (32 x f16x8 = 128 VGPR) ----
  f16x8 wf[4][8];
#pragma unroll
  for (int t = 0; t < 4; ++t)
#pragma unroll
    for (int ks = 0; ks < 8; ++ks) {
      const float* src = Whh + (size_t)(c0 + t*16 + fr) * RES
                       + q*256 + ks*32 + fk;
      const f32x4 w0 = *(const f32x4*)src;
      const f32x4 w1 = *(const f32x4*)(src + 4);
      f16x8 f;
#pragma unroll
      for (int j = 0; j < 4; ++j) { f[j] = (_Float16)w0[j]; f[4+j] = (_Float16)w1[j]; }
      wf[t][ks] = f;
    }

  unsigned* const fb = flags + g * (32 * 32);   // 32 cells x 128B per group

  for (int s = 0; s < SEQ; ++s) {
    // u prefetch: 1 float/thread, 32B-coalesced per 8 lanes
    const float u = states[(size_t)s * NB * RES + (size_t)(b0 + er) * RES + c0 + ec];

    f32x4 acc[4] = {};

    if (s > 0) {
      // ---- sentinel poll in fragment layout (full-line coverage) ----
      const _Float16* hp = ring + (size_t)((s - 1) & (RING - 1)) * (NB * RES)
                         + (size_t)(b0 + fr) * RES + q*256 + fk;
      f16x8 hv[8];
#pragma unroll
      for (int k = 0; k < 8; ++k) hv[k] = f16x8{};
      for (;;) {
        if (av) {
#pragma unroll
          for (int ks = 0; ks < 8; ++ks) {
            union { unsigned long long w[2]; f16x8 v; } au;
            au.w[0] = __hip_atomic_load((const unsigned long long*)(hp + ks*32),
                                        __ATOMIC_RELAXED, __HIP_MEMORY_SCOPE_AGENT);
            au.w[1] = __hip_atomic_load((const unsigned long long*)(hp + ks*32 + 4),
                                        __ATOMIC_RELAXED, __HIP_MEMORY_SCOPE_AGENT);
            hv[ks] = au.v;
          }
        }
        unsigned bad = 0;
        if (av) {
          const f16x8 ss = ((hv[0] + hv[1]) + (hv[2] + hv[3]))
                         + ((hv[4] + hv[5]) + (hv[6] + hv[7]));   // NaN propagates
          union { f16x8 v; unsigned w[4]; } su; su.v = ss;
#pragma unroll
          for (int j = 0; j < 4; ++j) {
            bad |= ((su.w[j] & 0x7C00u) == 0x7C00u);
            bad |= (((su.w[j] >> 16) & 0x7C00u) == 0x7C00u);
          }
        }
        if (!__any(bad)) break;
        __builtin_amdgcn_s_sleep(1);   // backoff: cap spin-load storm
      }
#pragma unroll
      for (int ks = 0; ks < 8; ++ks)
#pragma unroll
        for (int t = 0; t < 4; ++t)
          acc[t] = __builtin_amdgcn_mfma_f32_16x16x32_f16(hv[ks], wf[t][ks], acc[t], 0, 0, 0);
    }

    // ---- col-major partials: rows 0..7 only (lane>>4 < 2) ----
    const int p = s & 1;
    if ((lane >> 4) < 2) {
#pragma unroll
      for (int t = 0; t < 4; ++t) {
        float* dst = &red[p][q][t*16 + fr][(lane >> 4) * 4];
#pragma unroll
        for (int i = 0; i < 4; ++i) dst[i] = acc[t][i];
      }
    }
    __syncthreads();

    // ---- finalize: 1 value/thread ----
    float sum = u;
#pragma unroll
    for (int qq = 0; qq < 8; ++qq) sum += red[p][qq][ec][er];
    const float v = fast_tanh(sum);

    const size_t off = (size_t)(b0 + er) * RES + c0 + ec;
    states[(size_t)s * NB * RES + off] = v;               // states[s] (private)
    {
      unsigned short* hc = (unsigned short*)(ring + (size_t)(s & (RING - 1)) * (NB * RES));
      const _Float16 vh = (_Float16)v;
      __hip_atomic_store(hc + off, __builtin_bit_cast(unsigned short, vh),
                         __ATOMIC_RELAXED, __HIP_MEMORY_SCOPE_AGENT);
      if (s == SEQ - 1) hn[off] = v;
    }

    // poison slot s+4 (1 elem/thread). Ordering: completes before our own
    // step-s+1 poll passes (in-order vmcnt drain); consumers cannot reach
    // the slot's next valid read (their step s+5) until after our step-s+4
    // data stores, which postdate the poison.
    {
      unsigned short* pz = (unsigned short*)(ring
                         + (size_t)((s + 4) & (RING - 1)) * (NB * RES));
      __hip_atomic_store(pz + off, (unsigned short)0x7F7Fu,
                         __ATOMIC_RELAXED, __HIP_MEMORY_SCOPE_AGENT);
    }

    // ---- group re-alignment barrier every 8 steps (caps drift/spin) ----
    if ((s & 7) == 7 && s != SEQ - 1) {
      __syncthreads();   // whole WG done with step s
      if (wv == 0) {
        if (lane == 0)
          __hip_atomic_store(fb + idx * 32, (unsigned)((s >> 3) + 1),
                             __ATOMIC_RELAXED, __HIP_MEMORY_SCOPE_AGENT);
        const unsigned tgt = (unsigned)((s >> 3) + 1);
        const int cell = (lane < 32) ? lane : 0;
        for (;;) {
          const unsigned va = __hip_atomic_load(fb + cell * 32,
                                __ATOMIC_RELAXED, __HIP_MEMORY_SCOPE_AGENT);
          if (__all(va >= tgt)) break;
          __builtin_amdgcn_s_sleep(2);
        }
      }
      __syncthreads();   // release
    }
    // steady-state: no step-end barrier (red parity-dbuf, ring sentinel-gated)
  }
}

// ---------------------------------------------------------------------------
extern "C" void kernel_launch(void* const* d_in, const int* in_sizes, int n_in,
                              void* d_out, int out_size, void* d_ws, size_t ws_size,
                              hipStream_t stream) {
  const float* x    = (const float*)d_in[0];
  const float* W_in = (const float*)d_in[1];
  const float* W_hh = (const float*)d_in[2];
  const float* bias = (const float*)d_in[3];

  float* states = (float*)d_out;                        // [1024][64][2048]
  float* hn     = states + (size_t)SEQ * NB * RES;      // [64][2048]

  _Float16* ring  = (_Float16*)d_ws;                    // RING x [64][2048] fp16
  unsigned* flags = (unsigned*)((char*)d_ws
                  + (size_t)RING * NB * RES * sizeof(_Float16));

  hipMemsetAsync(ring, 0x7F, (size_t)RING * NB * RES * sizeof(_Float16), stream);
  hipMemsetAsync(flags, 0, (size_t)8 * 32 * 32 * sizeof(unsigned), stream);

  xin_gemm<<<dim3(512 * 16), dim3(256), 0, stream>>>(x, W_in, bias, states);
  esn_recur<<<dim3(256), dim3(512), 0, stream>>>(W_hh, states, hn, ring, flags);
}

// Round 10
// 6745.722 us; speedup vs baseline: 3.8922x; 1.1162x over previous
//
#include <hip/hip_runtime.h>
#include <hip/hip_bf16.h>

// ESN forward: states[s] = tanh(x[s] @ W_in^T + b + h_{s-1} @ W_hh^T)
// SEQ=1024, BATCH=64, IN=512, RES=2048, fp32 in/out.
// R10 = K4 (the 6679us round-4 kernel: best known-good) with its sync
// protocol byte-identical -- 4 batch-groups x 16 batches, 64 WGs x 32 cols,
// W_hh in VGPRs (wf[2][8]), ring-16 NaN-sentinel, no-backoff fragment-layout
// poll, 8-step flag barrier with bulk poison (waves 0/1) + wave-2 poller --
// and ONE WG-internal change: all-512-thread epilogue (col-major padded
// red[8][32][17], 1 output element/thread, coalesced publish) replacing the
// serial 2-wave epilogue. Consumers see identical bytes; protocol unchanged.

#define SEQ  1024
#define NB   64
#define INF  512
#define RES  2048
#define RING 16

typedef float    f32x4 __attribute__((ext_vector_type(4)));
typedef _Float16 f16x8 __attribute__((ext_vector_type(8)));

__device__ __forceinline__ float fast_tanh(float x) {
  const float e = __expf(2.0f * x);
  return 1.0f - 2.0f * __builtin_amdgcn_rcpf(1.0f + e);
}

// ---------------------------------------------------------------------------
// Kernel B: U = X @ Win^T + bias   (M=65536, N=2048, K=512), U -> d_out states
// ---------------------------------------------------------------------------
__global__ __launch_bounds__(256) void xin_gemm(
    const float* __restrict__ X, const float* __restrict__ Win,
    const float* __restrict__ bias, float* __restrict__ U)
{
  __shared__ _Float16 lA[2][128][40];
  __shared__ _Float16 lB[2][128][40];

  const int tid  = threadIdx.x;
  const int lane = tid & 63;
  const int wv   = tid >> 6;
  const int wr   = wv >> 1;
  const int wc   = wv & 1;
  const int m0   = (blockIdx.x >> 4) * 128;
  const int n0   = (blockIdx.x & 15) * 128;

  const int srow = tid >> 1;
  const int sk   = (tid & 1) * 16;

  const int fr = lane & 15;
  const int fk = (lane >> 4) * 8;

  f32x4 acc[4][4] = {};
  float ra[16], rb[16];

  const float* xa_base = X   + (size_t)(m0 + srow) * INF + sk;
  const float* xb_base = Win + (size_t)(n0 + srow) * INF + sk;

#define LOADK(kt) do {                                                     \
    const float* pa = xa_base + (kt) * 32;                                 \
    const float* pb = xb_base + (kt) * 32;                                 \
    *(f32x4*)&ra[0]  = *(const f32x4*)(pa + 0);                            \
    *(f32x4*)&ra[4]  = *(const f32x4*)(pa + 4);                            \
    *(f32x4*)&ra[8]  = *(const f32x4*)(pa + 8);                            \
    *(f32x4*)&ra[12] = *(const f32x4*)(pa + 12);                           \
    *(f32x4*)&rb[0]  = *(const f32x4*)(pb + 0);                            \
    *(f32x4*)&rb[4]  = *(const f32x4*)(pb + 4);                            \
    *(f32x4*)&rb[8]  = *(const f32x4*)(pb + 8);                            \
    *(f32x4*)&rb[12] = *(const f32x4*)(pb + 12);                           \
  } while (0)

#define STOREK(buf) do {                                                   \
    f16x8 h0, h1;                                                          \
    _Pragma("unroll") for (int j = 0; j < 8; ++j) h0[j] = (_Float16)ra[j]; \
    _Pragma("unroll") for (int j = 0; j < 8; ++j) h1[j] = (_Float16)ra[8+j];\
    *(f16x8*)&lA[buf][srow][sk]     = h0;                                  \
    *(f16x8*)&lA[buf][srow][sk + 8] = h1;                                  \
    _Pragma("unroll") for (int j = 0; j < 8; ++j) h0[j] = (_Float16)rb[j]; \
    _Pragma("unroll") for (int j = 0; j < 8; ++j) h1[j] = (_Float16)rb[8+j];\
    *(f16x8*)&lB[buf][srow][sk]     = h0;                                  \
    *(f16x8*)&lB[buf][srow][sk + 8] = h1;                                  \
  } while (0)

#define COMPUTE(buf) do {                                                  \
    f16x8 af[4], bf[4];                                                    \
    _Pragma("unroll") for (int mt = 0; mt < 4; ++mt)                       \
      af[mt] = *(const f16x8*)&lA[buf][wr*64 + mt*16 + fr][fk];            \
    _Pragma("unroll") for (int nt = 0; nt < 4; ++nt)                       \
      bf[nt] = *(const f16x8*)&lB[buf][wc*64 + nt*16 + fr][fk];            \
    _Pragma("unroll") for (int mt = 0; mt < 4; ++mt)                       \
      _Pragma("unroll") for (int nt = 0; nt < 4; ++nt)                     \
        acc[mt][nt] = __builtin_amdgcn_mfma_f32_16x16x32_f16(              \
            af[mt], bf[nt], acc[mt][nt], 0, 0, 0);                         \
  } while (0)

  LOADK(0);
  STOREK(0);
  __syncthreads();

#pragma unroll 1
  for (int kt = 0; kt < 16; ++kt) {
    const int buf = kt & 1;
    if (kt < 15) LOADK(kt + 1);
    COMPUTE(buf);
    if (kt < 15) STOREK(buf ^ 1);
    __syncthreads();
  }

#pragma unroll
  for (int mt = 0; mt < 4; ++mt) {
    const int row = m0 + wr*64 + mt*16 + (lane >> 4) * 4;
#pragma unroll
    for (int nt = 0; nt < 4; ++nt) {
      const int col = n0 + wc*64 + nt*16 + fr;
      const float bv = bias[col];
#pragma unroll
      for (int i = 0; i < 4; ++i)
        U[(size_t)(row + i) * RES + col] = acc[mt][nt][i] + bv;
    }
  }
#undef LOADK
#undef STOREK
#undef COMPUTE
}

// ---------------------------------------------------------------------------
// Kernel C: persistent recurrence. 256 WGs x 512 thr, 1 WG/CU.
// WG = (batch group bg: 16 batches) x (cols c0..c0+32). Wave q = K-eighth.
// A-frags polled directly from NaN-sentinel ring-16 (all 64 lanes, no
// backoff); B = wf[2][8] in VGPR; 16 MFMA/wave/step.
// Epilogue: all 512 threads -- red[8][32][17] col-major, 1 value/thread
// (er=tid>>5, ec=tid&31), coalesced states/h stores.
// Barrier every 8 steps: waves 0/1 bulk-poison slots s+1..s+8 (own slice),
// vmcnt(0) drain, raise per-WG flag cell; wave 2 polls all 128 group cells.
// ---------------------------------------------------------------------------
__global__ __launch_bounds__(512, 1) void esn_recur(
    const float* __restrict__ Whh, float* __restrict__ states,
    float* __restrict__ hn, _Float16* __restrict__ ring,
    unsigned* __restrict__ flags)
{
  __shared__ float red[8][32][17];   // 17.4 KB, odd pad -> <=2-way banks

  const int tid  = threadIdx.x;
  const int lane = tid & 63;
  const int wv   = tid >> 6;        // wave = K-eighth q
  const int q    = wv;

  const int bid = blockIdx.x;
  const int xg  = bid & 7;
  const int bg  = xg >> 1;                        // batch group 0..3
  const int cg  = ((xg & 1) << 5) | (bid >> 3);   // col group 0..63 (bijective)
  const int b0  = bg * 16;
  const int c0  = cg * 32;

  const int fr = lane & 15;
  const int fk = (lane >> 4) * 8;

  const int er = tid >> 5;          // epilogue batch row 0..15
  const int ec = tid & 31;          // epilogue col 0..31

  // ---- one-time: W_hh fragments -> VGPRs (16 x f16x8 = 64 VGPR) ----
  f16x8 wf[2][8];
#pragma unroll
  for (int t = 0; t < 2; ++t)
#pragma unroll
    for (int ks = 0; ks < 8; ++ks) {
      const float* src = Whh + (size_t)(c0 + t*16 + fr) * RES
                       + q*256 + ks*32 + fk;
      const f32x4 w0 = *(const f32x4*)src;
      const f32x4 w1 = *(const f32x4*)(src + 4);
      f16x8 f;
#pragma unroll
      for (int j = 0; j < 4; ++j) { f[j] = (_Float16)w0[j]; f[4+j] = (_Float16)w1[j]; }
      wf[t][ks] = f;
    }

  unsigned* const fb = flags + bg * (128 * 32);   // 128 cells x 128B per group

  for (int s = 0; s < SEQ; ++s) {
    // u prefetch: 1 float/thread, coalesced; overlaps poll+MFMA
    const float u = states[(size_t)s * NB * RES + (size_t)(b0 + er) * RES + c0 + ec];

    f32x4 a0 = {0.f, 0.f, 0.f, 0.f}, a1 = {0.f, 0.f, 0.f, 0.f};

    if (s > 0) {
      // ---- sentinel poll, fragment layout, all 64 lanes, no backoff ----
      const _Float16* hp = ring + (size_t)((s - 1) & (RING - 1)) * (NB * RES)
                         + (size_t)(b0 + fr) * RES + q*256 + fk;
      f16x8 hv[8];
      for (;;) {
#pragma unroll
        for (int ks = 0; ks < 8; ++ks) {
          union { unsigned long long w[2]; f16x8 v; } au;
          au.w[0] = __hip_atomic_load((const unsigned long long*)(hp + ks*32),
                                      __ATOMIC_RELAXED, __HIP_MEMORY_SCOPE_AGENT);
          au.w[1] = __hip_atomic_load((const unsigned long long*)(hp + ks*32 + 4),
                                      __ATOMIC_RELAXED, __HIP_MEMORY_SCOPE_AGENT);
          hv[ks] = au.v;
        }
        const f16x8 ss = ((hv[0] + hv[1]) + (hv[2] + hv[3]))
                       + ((hv[4] + hv[5]) + (hv[6] + hv[7]));   // NaN propagates
        union { f16x8 v; unsigned w[4]; } su; su.v = ss;
        unsigned bad = 0;
#pragma unroll
        for (int j = 0; j < 4; ++j) {
          bad |= ((su.w[j] & 0x7C00u) == 0x7C00u);
          bad |= (((su.w[j] >> 16) & 0x7C00u) == 0x7C00u);
        }
        if (!__any(bad)) break;
      }
#pragma unroll
      for (int ks = 0; ks < 8; ++ks) {
        a0 = __builtin_amdgcn_mfma_f32_16x16x32_f16(hv[ks], wf[0][ks], a0, 0, 0, 0);
        a1 = __builtin_amdgcn_mfma_f32_16x16x32_f16(hv[ks], wf[1][ks], a1, 0, 0, 0);
      }
    }

    // ---- col-major partials: red[q][col][row] (C/D: col=lane&15,
    //      row=(lane>>4)*4+i) ----
    {
      const int r4 = (lane >> 4) * 4;
      float* d0 = &red[q][fr][r4];
      float* d1 = &red[q][16 + fr][r4];
#pragma unroll
      for (int i = 0; i < 4; ++i) { d0[i] = a0[i]; d1[i] = a1[i]; }
    }
    __syncthreads();   // red ready

    // ---- finalize: 1 value/thread ----
    float sum = u;
#pragma unroll
    for (int qq = 0; qq < 8; ++qq) sum += red[qq][ec][er];
    const float v = fast_tanh(sum);

    const size_t off = (size_t)(b0 + er) * RES + c0 + ec;
    states[(size_t)s * NB * RES + off] = v;               // private slice
    {
      unsigned short* hc = (unsigned short*)(ring
                         + (size_t)(s & (RING - 1)) * (NB * RES));
      const unsigned short hb = __builtin_bit_cast(unsigned short, (_Float16)v);
      __hip_atomic_store(hc + off, hb,
                         __ATOMIC_RELAXED, __HIP_MEMORY_SCOPE_AGENT);
      if (s == SEQ - 1) hn[off] = v;
    }

    // ---- 8-step barrier: bulk poison + flags (K4 protocol, verbatim) ----
    const bool barrier_step = ((s & 7) == 7) && (s != SEQ - 1);
    if (barrier_step) {
      if (wv < 2) {
        const int col = c0 + wv * 16 + fr;
        // poison stale slots (s+1..s+8) mod 16 (own 16-row x 16-col slice)
#pragma unroll
        for (int d = 1; d <= 8; ++d) {
          unsigned short* pz = (unsigned short*)(ring
                             + (size_t)((s + d) & (RING - 1)) * (NB * RES));
#pragma unroll
          for (int i = 0; i < 4; ++i) {
            const size_t poff = (size_t)(b0 + (lane >> 4) * 4 + i) * RES + col;
            __hip_atomic_store(&pz[poff], (unsigned short)0x7F7Fu,
                               __ATOMIC_RELAXED, __HIP_MEMORY_SCOPE_AGENT);
          }
        }
        asm volatile("s_waitcnt vmcnt(0)" ::: "memory");   // poison visible
        if (lane == 0)
          __hip_atomic_store(fb + (wv * 64 + cg) * 32, (unsigned)((s >> 3) + 1),
                             __ATOMIC_RELAXED, __HIP_MEMORY_SCOPE_AGENT);
      } else if (wv == 2) {
        // dedicated poller: two wave-wide gathers cover all 128 group flags
        const unsigned tgt = (unsigned)((s >> 3) + 1);
        for (;;) {
          const unsigned va = __hip_atomic_load(fb + lane * 32,
                                __ATOMIC_RELAXED, __HIP_MEMORY_SCOPE_AGENT);
          const unsigned vb = __hip_atomic_load(fb + (64 + lane) * 32,
                                __ATOMIC_RELAXED, __HIP_MEMORY_SCOPE_AGENT);
          if (__all((va >= tgt) & (vb >= tgt))) break;
        }
      }
    }
    __syncthreads();   // releases all waves; next step's red writes follow
  }
}

// ---------------------------------------------------------------------------
extern "C" void kernel_launch(void* const* d_in, const int* in_sizes, int n_in,
                              void* d_out, int out_size, void* d_ws, size_t ws_size,
                              hipStream_t stream) {
  const float* x    = (const float*)d_in[0];
  const float* W_in = (const float*)d_in[1];
  const float* W_hh = (const float*)d_in[2];
  const float* bias = (const float*)d_in[3];

  float* states = (float*)d_out;                        // [1024][64][2048]
  float* hn     = states + (size_t)SEQ * NB * RES;      // [64][2048]

  _Float16* ring  = (_Float16*)d_ws;                    // RING x [64][2048] fp16
  unsigned* flags = (unsigned*)((char*)d_ws
                  + (size_t)RING * NB * RES * sizeof(_Float16));

  // sentinel-init ring (0x7F7F = fp16 NaN), zero flags
  hipMemsetAsync(ring, 0x7F, (size_t)RING * NB * RES * sizeof(_Float16), stream);
  hipMemsetAsync(flags, 0, (size_t)4 * 128 * 32 * sizeof(unsigned), stream);

  xin_gemm<<<dim3(512 * 16), dim3(256), 0, stream>>>(x, W_in, bias, states);
  esn_recur<<<dim3(256), dim3(512), 0, stream>>>(W_hh, states, hn, ring, flags);
}

// Round 11
// 6337.294 us; speedup vs baseline: 4.1431x; 1.0644x over previous
//
#include <hip/hip_runtime.h>
#include <hip/hip_bf16.h>

// ESN forward: states[s] = tanh(x[s] @ W_in^T + b + h_{s-1} @ W_hh^T)
// SEQ=1024, BATCH=64, IN=512, RES=2048, fp32 in/out.
// R11 = R10 (known-good: 4 batch-groups x 16 batches, 64 WGs x 32 cols,
// W_hh in VGPRs, ring-16 NaN-sentinel fragment-layout poll, 8-step flag
// barrier with bulk poison, all-thread epilogue) + FUSED input projection:
// the separate xin_gemm (350us serialized ahead of the recurrence) is
// deleted; each wave adds its K-slice of x[s]@Win^T (IN=512 = 8 waves x 64)
// as 4 extra MFMAs into the same accumulators. Win frags (16 VGPR) loaded
// once; bias folded into epilogue; x-frag loads issue before the poll and
// hide under the wait. Sync protocol is byte-identical to R10.

#define SEQ  1024
#define NB   64
#define INF  512
#define RES  2048
#define RING 16

typedef float    f32x4 __attribute__((ext_vector_type(4)));
typedef _Float16 f16x8 __attribute__((ext_vector_type(8)));

__device__ __forceinline__ float fast_tanh(float x) {
  const float e = __expf(2.0f * x);
  return 1.0f - 2.0f * __builtin_amdgcn_rcpf(1.0f + e);
}

// ---------------------------------------------------------------------------
// Persistent fused kernel: 256 WGs x 512 thr, 1 WG/CU.
// WG = (batch group bg: 16 batches) x (cols c0..c0+32). Wave q = K-eighth.
// Per step: A-frags of h_{s-1} polled from NaN-sentinel ring-16 (all 64
// lanes, no backoff); B = wf[2][8] (W_hh) + winf[2][2] (W_in) in VGPR;
// 16 + 4 MFMA/wave/step. Epilogue: all 512 threads, red[8][32][17]
// col-major, 1 value/thread, v = tanh(bias + sum); coalesced publish.
// Barrier every 8 steps: waves 0/1 bulk-poison slots s+1..s+8 (own slice),
// vmcnt(0) drain, raise per-WG flag cell; wave 2 polls all 128 group cells.
// ---------------------------------------------------------------------------
__global__ __launch_bounds__(512, 1) void esn_recur(
    const float* __restrict__ X, const float* __restrict__ Whh,
    const float* __restrict__ Win, const float* __restrict__ bias,
    float* __restrict__ states, float* __restrict__ hn,
    _Float16* __restrict__ ring, unsigned* __restrict__ flags)
{
  __shared__ float red[8][32][17];   // 17.4 KB, odd pad -> <=2-way banks

  const int tid  = threadIdx.x;
  const int lane = tid & 63;
  const int wv   = tid >> 6;        // wave = K-eighth q
  const int q    = wv;

  const int bid = blockIdx.x;
  const int xg  = bid & 7;
  const int bg  = xg >> 1;                        // batch group 0..3
  const int cg  = ((xg & 1) << 5) | (bid >> 3);   // col group 0..63 (bijective)
  const int b0  = bg * 16;
  const int c0  = cg * 32;

  const int fr = lane & 15;
  const int fk = (lane >> 4) * 8;

  const int er = tid >> 5;          // epilogue batch row 0..15
  const int ec = tid & 31;          // epilogue col 0..31

  // ---- one-time: W_hh fragments -> VGPRs (16 x f16x8 = 64 VGPR) ----
  f16x8 wf[2][8];
#pragma unroll
  for (int t = 0; t < 2; ++t)
#pragma unroll
    for (int ks = 0; ks < 8; ++ks) {
      const float* src = Whh + (size_t)(c0 + t*16 + fr) * RES
                       + q*256 + ks*32 + fk;
      const f32x4 w0 = *(const f32x4*)src;
      const f32x4 w1 = *(const f32x4*)(src + 4);
      f16x8 f;
#pragma unroll
      for (int j = 0; j < 4; ++j) { f[j] = (_Float16)w0[j]; f[4+j] = (_Float16)w1[j]; }
      wf[t][ks] = f;
    }

  // ---- one-time: W_in fragments, K-slice [q*64, q*64+64) (4 x f16x8) ----
  f16x8 winf[2][2];
#pragma unroll
  for (int t = 0; t < 2; ++t)
#pragma unroll
    for (int ks = 0; ks < 2; ++ks) {
      const float* src = Win + (size_t)(c0 + t*16 + fr) * INF
                       + q*64 + ks*32 + fk;
      const f32x4 w0 = *(const f32x4*)src;
      const f32x4 w1 = *(const f32x4*)(src + 4);
      f16x8 f;
#pragma unroll
      for (int j = 0; j < 4; ++j) { f[j] = (_Float16)w0[j]; f[4+j] = (_Float16)w1[j]; }
      winf[t][ks] = f;
    }

  // ---- one-time: bias for this thread's epilogue element ----
  const float bv = bias[c0 + ec];

  unsigned* const fb = flags + bg * (128 * 32);   // 128 cells x 128B per group

  for (int s = 0; s < SEQ; ++s) {
    // ---- x fragment load (fp32), issued before the poll to hide latency ----
    f32x4 xr0a, xr0b, xr1a, xr1b;
    {
      const float* xp = X + (size_t)s * (NB * INF)
                      + (size_t)(b0 + fr) * INF + q*64 + fk;
      xr0a = *(const f32x4*)(xp);
      xr0b = *(const f32x4*)(xp + 4);
      xr1a = *(const f32x4*)(xp + 32);
      xr1b = *(const f32x4*)(xp + 36);
    }

    f32x4 a0 = {0.f, 0.f, 0.f, 0.f}, a1 = {0.f, 0.f, 0.f, 0.f};

    if (s > 0) {
      // ---- sentinel poll, fragment layout, all 64 lanes, no backoff ----
      const _Float16* hp = ring + (size_t)((s - 1) & (RING - 1)) * (NB * RES)
                         + (size_t)(b0 + fr) * RES + q*256 + fk;
      f16x8 hv[8];
      for (;;) {
#pragma unroll
        for (int ks = 0; ks < 8; ++ks) {
          union { unsigned long long w[2]; f16x8 v; } au;
          au.w[0] = __hip_atomic_load((const unsigned long long*)(hp + ks*32),
                                      __ATOMIC_RELAXED, __HIP_MEMORY_SCOPE_AGENT);
          au.w[1] = __hip_atomic_load((const unsigned long long*)(hp + ks*32 + 4),
                                      __ATOMIC_RELAXED, __HIP_MEMORY_SCOPE_AGENT);
          hv[ks] = au.v;
        }
        const f16x8 ss = ((hv[0] + hv[1]) + (hv[2] + hv[3]))
                       + ((hv[4] + hv[5]) + (hv[6] + hv[7]));   // NaN propagates
        union { f16x8 v; unsigned w[4]; } su; su.v = ss;
        unsigned bad = 0;
#pragma unroll
        for (int j = 0; j < 4; ++j) {
          bad |= ((su.w[j] & 0x7C00u) == 0x7C00u);
          bad |= (((su.w[j] >> 16) & 0x7C00u) == 0x7C00u);
        }
        if (!__any(bad)) break;
      }
#pragma unroll
      for (int ks = 0; ks < 8; ++ks) {
        a0 = __builtin_amdgcn_mfma_f32_16x16x32_f16(hv[ks], wf[0][ks], a0, 0, 0, 0);
        a1 = __builtin_amdgcn_mfma_f32_16x16x32_f16(hv[ks], wf[1][ks], a1, 0, 0, 0);
      }
    }

    // ---- fused input projection: x[s] K-slice @ Win^T (4 MFMA) ----
    {
      f16x8 xa0, xa1;
#pragma unroll
      for (int j = 0; j < 4; ++j) {
        xa0[j] = (_Float16)xr0a[j]; xa0[4+j] = (_Float16)xr0b[j];
        xa1[j] = (_Float16)xr1a[j]; xa1[4+j] = (_Float16)xr1b[j];
      }
      a0 = __builtin_amdgcn_mfma_f32_16x16x32_f16(xa0, winf[0][0], a0, 0, 0, 0);
      a0 = __builtin_amdgcn_mfma_f32_16x16x32_f16(xa1, winf[0][1], a0, 0, 0, 0);
      a1 = __builtin_amdgcn_mfma_f32_16x16x32_f16(xa0, winf[1][0], a1, 0, 0, 0);
      a1 = __builtin_amdgcn_mfma_f32_16x16x32_f16(xa1, winf[1][1], a1, 0, 0, 0);
    }

    // ---- col-major partials: red[q][col][row] (C/D: col=lane&15,
    //      row=(lane>>4)*4+i) ----
    {
      const int r4 = (lane >> 4) * 4;
      float* d0 = &red[q][fr][r4];
      float* d1 = &red[q][16 + fr][r4];
#pragma unroll
      for (int i = 0; i < 4; ++i) { d0[i] = a0[i]; d1[i] = a1[i]; }
    }
    __syncthreads();   // red ready

    // ---- finalize: 1 value/thread ----
    float sum = bv;
#pragma unroll
    for (int qq = 0; qq < 8; ++qq) sum += red[qq][ec][er];
    const float v = fast_tanh(sum);

    const size_t off = (size_t)(b0 + er) * RES + c0 + ec;
    states[(size_t)s * NB * RES + off] = v;               // private slice
    {
      unsigned short* hc = (unsigned short*)(ring
                         + (size_t)(s & (RING - 1)) * (NB * RES));
      const unsigned short hb = __builtin_bit_cast(unsigned short, (_Float16)v);
      __hip_atomic_store(hc + off, hb,
                         __ATOMIC_RELAXED, __HIP_MEMORY_SCOPE_AGENT);
      if (s == SEQ - 1) hn[off] = v;
    }

    // ---- 8-step barrier: bulk poison + flags (R10 protocol, verbatim) ----
    const bool barrier_step = ((s & 7) == 7) && (s != SEQ - 1);
    if (barrier_step) {
      if (wv < 2) {
        const int col = c0 + wv * 16 + fr;
        // poison stale slots (s+1..s+8) mod 16 (own 16-row x 16-col slice)
#pragma unroll
        for (int d = 1; d <= 8; ++d) {
          unsigned short* pz = (unsigned short*)(ring
                             + (size_t)((s + d) & (RING - 1)) * (NB * RES));
#pragma unroll
          for (int i = 0; i < 4; ++i) {
            const size_t poff = (size_t)(b0 + (lane >> 4) * 4 + i) * RES + col;
            __hip_atomic_store(&pz[poff], (unsigned short)0x7F7Fu,
                               __ATOMIC_RELAXED, __HIP_MEMORY_SCOPE_AGENT);
          }
        }
        asm volatile("s_waitcnt vmcnt(0)" ::: "memory");   // poison visible
        if (lane == 0)
          __hip_atomic_store(fb + (wv * 64 + cg) * 32, (unsigned)((s >> 3) + 1),
                             __ATOMIC_RELAXED, __HIP_MEMORY_SCOPE_AGENT);
      } else if (wv == 2) {
        // dedicated poller: two wave-wide gathers cover all 128 group flags
        const unsigned tgt = (unsigned)((s >> 3) + 1);
        for (;;) {
          const unsigned va = __hip_atomic_load(fb + lane * 32,
                                __ATOMIC_RELAXED, __HIP_MEMORY_SCOPE_AGENT);
          const unsigned vb = __hip_atomic_load(fb + (64 + lane) * 32,
                                __ATOMIC_RELAXED, __HIP_MEMORY_SCOPE_AGENT);
          if (__all((va >= tgt) & (vb >= tgt))) break;
        }
      }
    }
    __syncthreads();   // releases all waves; next step's red writes follow
  }
}

// ---------------------------------------------------------------------------
extern "C" void kernel_launch(void* const* d_in, const int* in_sizes, int n_in,
                              void* d_out, int out_size, void* d_ws, size_t ws_size,
                              hipStream_t stream) {
  const float* x    = (const float*)d_in[0];   // [1024][64][512]
  const float* W_in = (const float*)d_in[1];   // [2048][512]
  const float* W_hh = (const float*)d_in[2];   // [2048][2048]
  const float* bias = (const float*)d_in[3];   // [2048]

  float* states = (float*)d_out;                        // [1024][64][2048]
  float* hn     = states + (size_t)SEQ * NB * RES;      // [64][2048]

  _Float16* ring  = (_Float16*)d_ws;                    // RING x [64][2048] fp16
  unsigned* flags = (unsigned*)((char*)d_ws
                  + (size_t)RING * NB * RES * sizeof(_Float16));

  // sentinel-init ring (0x7F7F = fp16 NaN), zero flags
  hipMemsetAsync(ring, 0x7F, (size_t)RING * NB * RES * sizeof(_Float16), stream);
  hipMemsetAsync(flags, 0, (size_t)4 * 128 * 32 * sizeof(unsigned), stream);

  esn_recur<<<dim3(256), dim3(512), 0, stream>>>(x, W_hh, W_in, bias,
                                                 states, hn, ring, flags);
}